// Round 1
// baseline (142.554 us; speedup 1.0000x reference)
//
#include <hip/hip_runtime.h>

// Rowwise cosine similarity: out[r] = dot(a_r,b_r) * rsqrt(max(|a_r|^2,eps)) * rsqrt(max(|b_r|^2,eps))
// a, b: [16, 4096, 256] f32 contiguous -> 65536 rows of 256 floats.
//
// Mapping (v2): 8 rows per wave, 8 lanes per row, 8 float4 per lane.
//  - Each wave issues 16 independent global_load_dwordx4 (16 KB in flight)
//    before waiting -> 8x memory parallelism vs one-row-per-wave.
//  - Each unrolled load step: every 8-lane group reads one full 128B cache
//    line (8 x 16B contiguous); wave reads 8 such segments -> fully coalesced.
//  - Reduction: only 3 butterfly steps (xor 1,2,4 within the 8-lane group)
//    for 8 rows, vs 6 steps *per row* before (16x fewer shuffles per row).

#define D          256
#define D4         64          // float4s per row
#define EPS        1e-12f
#define LANES_ROW  8           // lanes cooperating on one row
#define ROWS_WAVE  8           // rows per wave (64 / LANES_ROW)
#define F4_LANE    8           // float4s per lane (D4 / LANES_ROW)
#define WAVES_BLK  4           // 256 threads

__global__ __launch_bounds__(256) void cosine_rows_kernel(
    const float* __restrict__ a,
    const float* __restrict__ b,
    float* __restrict__ out,
    int n_rows)
{
    const int lane = threadIdx.x & 63;
    const int wave = threadIdx.x >> 6;
    const int g    = lane >> 3;        // row index within this wave's batch
    const int s    = lane & 7;         // sublane within the row

    const int row = (blockIdx.x * WAVES_BLK + wave) * ROWS_WAVE + g;
    if (row >= n_rows) return;

    const float4* a4 = reinterpret_cast<const float4*>(a) + (size_t)row * D4 + s;
    const float4* b4 = reinterpret_cast<const float4*>(b) + (size_t)row * D4 + s;

    // Issue all 16 loads up front (compiler keeps them in flight together).
    float4 av[F4_LANE], bv[F4_LANE];
    #pragma unroll
    for (int k = 0; k < F4_LANE; ++k) {
        av[k] = a4[k * LANES_ROW];     // stride 8 float4s = 128B: lane-group
        bv[k] = b4[k * LANES_ROW];     // covers one full cache line per step
    }

    float sa = 0.f, sb = 0.f, sab = 0.f;
    #pragma unroll
    for (int k = 0; k < F4_LANE; ++k) {
        sa  += av[k].x * av[k].x + av[k].y * av[k].y + av[k].z * av[k].z + av[k].w * av[k].w;
        sb  += bv[k].x * bv[k].x + bv[k].y * bv[k].y + bv[k].z * bv[k].z + bv[k].w * bv[k].w;
        sab += av[k].x * bv[k].x + av[k].y * bv[k].y + av[k].z * bv[k].z + av[k].w * bv[k].w;
    }

    // 3-step butterfly within the 8-lane group (groups are xor-aligned).
    #pragma unroll
    for (int off = 1; off < LANES_ROW; off <<= 1) {
        sa  += __shfl_xor(sa,  off, 64);
        sb  += __shfl_xor(sb,  off, 64);
        sab += __shfl_xor(sab, off, 64);
    }

    if (s == 0) {
        out[row] = sab * rsqrtf(fmaxf(sa, EPS)) * rsqrtf(fmaxf(sb, EPS));
    }
}

extern "C" void kernel_launch(void* const* d_in, const int* in_sizes, int n_in,
                              void* d_out, int out_size, void* d_ws, size_t ws_size,
                              hipStream_t stream)
{
    const float* a = (const float*)d_in[0];
    const float* b = (const float*)d_in[1];
    float* out = (float*)d_out;

    const int n_rows = out_size;                        // 16 * 4096 = 65536
    const int rows_per_block = WAVES_BLK * ROWS_WAVE;   // 32
    const int grid = (n_rows + rows_per_block - 1) / rows_per_block;

    cosine_rows_kernel<<<grid, 256, 0, stream>>>(a, b, out, n_rows);
}